// Round 7
// baseline (4368.419 us; speedup 1.0000x reference)
//
#include <hip/hip_runtime.h>
#include <cstddef>

typedef _Float16 f16;
typedef _Float16 f16x8 __attribute__((ext_vector_type(8)));
typedef _Float16 f16x4 __attribute__((ext_vector_type(4)));
typedef float f32x4 __attribute__((ext_vector_type(4)));

#define T_STEPS 512
#define BATCH   64
#define DD      1024
#define NTOT    4096   // 4 gates * D, n = d*4 + g (g: 0=i,1=f,2=c,3=o)

// Decomposition: 4 independent groups of 16 batch rows (batch elements are
// independent LSTM chains). Group g = blockIdx&3, member j2 = blockIdx>>2
// (0..63). WG (g,j2) owns gate cols [64*j2, 64*j2+64) = h cols [16*j2,+16)
// for batch rows [16g, 16g+16).
// Sync is DATAFLOW: k-chunk c of the recurrent GEMM needs only producers
// 16c..16c+16; each chunk is polled inline, overlapping skew + load latency
// with MFMA work. No full-group barrier exists.

// h ring: one fresh slot per step -> plain cached reads can never hit a stale
// line -> NO acquire fence / L2 invalidate anywhere.
#define RSTRIDE_B 139264ull                        // 136 KB per slot (page multiple)
#define RSTRIDE_H 69632ull                         // in f16 units
#define GSLAB_H   16384ull                         // group slab: 16*1024 f16

// ---- workspace layout (bytes); total < proven 356.8 MB budget ----
#define OFF_FLAGS 0ull                             // 4096 u32 = 16 KB flag lines
#define OFF_BIAS  16384ull                         // 4096 f32
#define OFF_WHP   32768ull                         // 8 MB
#define OFF_BXP   (OFF_WHP + 8388608ull)           // 8 MB
#define OFF_XW    (OFF_BXP + 8388608ull)           // 32768*4096 f16 = 256 MB
#define XW_END    (OFF_XW + 268435456ull)
#define OFF_RING  XW_END                           // 512 slots * 136 KB = 68 MB
#define RING_END  (OFF_RING + 512ull * RSTRIDE_B)  // ~356.5 MB total

// flags (u32 indices): group g, member j2 -> flags[g*1024 + j2*16] (own 64B line)
// value = t+1 after member wrote its h sliver for ring slot t+1.

__device__ __forceinline__ float sigm(float x) { return 1.f / (1.f + __expf(-x)); }
__device__ __forceinline__ float tanh_fast(float x) {
    float e = __expf(-2.f * fabsf(x));
    float t = (1.f - e) / (1.f + e);
    return x >= 0.f ? t : -t;
}

// coherent (cross-XCD) primitives: relaxed agent-scope atomics -> sc0 sc1
__device__ __forceinline__ unsigned int load_coh_u32(const unsigned int* p) {
    return __hip_atomic_load((unsigned int*)p, __ATOMIC_RELAXED, __HIP_MEMORY_SCOPE_AGENT);
}
__device__ __forceinline__ void store_coh_u32(unsigned int* p, unsigned int v) {
    __hip_atomic_store(p, v, __ATOMIC_RELAXED, __HIP_MEMORY_SCOPE_AGENT);
}
__device__ __forceinline__ void store_coh_u64(unsigned long long* p, unsigned long long v) {
    __hip_atomic_store(p, v, __ATOMIC_RELAXED, __HIP_MEMORY_SCOPE_AGENT);
}
__device__ __forceinline__ void waitcnt_vm0() {
    asm volatile("s_waitcnt vmcnt(0)" ::: "memory");
}

// one LSTM cell for 1 output column: gates (i,f,c,o) in g4, x-contribution x0..x3
#define GATE4(g4, x0, x1, x2, x3, cvar, hvar)                        \
    {                                                                \
        float pi = (g4).x + (float)(x0);                             \
        float pf = (g4).y + (float)(x1);                             \
        float pg = (g4).z + (float)(x2);                             \
        float po = (g4).w + (float)(x3);                             \
        float iv = sigm(pi), fv = sigm(pf);                          \
        float gg = tanh_fast(pg), ov = sigm(po);                     \
        cvar = fv * cvar + iv * gg;                                  \
        hvar = ov * tanh_fast(cvar);                                 \
    }

// ---------------------------------------------------------------------------
// Prepack: weights -> f16 fragment order (B-frag for mfma_f32_16x16x32_f16:
// lane l holds B[k=S*32+(l>>4)*8+jj][n=NT*16+(l&15)] at arr[((NT*32+S)*64+l)*8+jj]).
// ring0: h_0 = tanh(c0) broadcast; linear [b][d] == grouped slab layout.
// ---------------------------------------------------------------------------
__global__ void prepack_kernel(const float* __restrict__ Wi, const float* __restrict__ Wf,
                               const float* __restrict__ Wc, const float* __restrict__ Wo,
                               const float* __restrict__ bi, const float* __restrict__ bf,
                               const float* __restrict__ bc, const float* __restrict__ bo,
                               const float* __restrict__ c0,
                               f16* __restrict__ whp, f16* __restrict__ bxp,
                               float* __restrict__ biasp, f16* __restrict__ ring0,
                               unsigned int* __restrict__ flags)
{
    unsigned int gid = blockIdx.x * 256u + threadIdx.x;
    if (gid < 4096u) flags[gid] = 0u;             // zero flag region each launch (graph replay)
    const float* Ww[4] = {Wi, Wf, Wc, Wo};
    if (gid < 8388608u) {
        unsigned int hi = (gid >= 4194304u);      // 0 -> bxp (k 0..1023), 1 -> whp (k 1024..2047)
        unsigned int e  = gid & 4194303u;
        unsigned int jj = e & 7u;
        unsigned int lidx = (e >> 3) & 63u;
        unsigned int S  = (e >> 9) & 31u;
        unsigned int NT = e >> 14;
        unsigned int n  = NT * 16u + (lidx & 15u);
        unsigned int k  = S * 32u + (lidx >> 4) * 8u + jj + (hi ? 1024u : 0u);
        unsigned int g  = n & 3u, d = n >> 2;
        float v = Ww[g][k * 1024u + d];
        (hi ? whp : bxp)[e] = (f16)v;
    } else if (gid < 8392704u) {                  // bias: 4096
        unsigned int n = gid - 8388608u;
        const float* Bb[4] = {bi, bf, bc, bo};
        biasp[n] = Bb[n & 3u][n >> 2];
    } else if (gid < 8458240u) {                  // h_0[b][d] = tanh(c0[d]) : 65536
        unsigned int e2 = gid - 8392704u;
        ring0[e2] = (f16)tanh_fast(c0[e2 & 1023u]);
    }
}

// ---------------------------------------------------------------------------
// Phase 1: xw[m][n] = batch[m][:1024] @ Wx[:, n] + bias[n]   (f16 out)
// ---------------------------------------------------------------------------
__global__ __launch_bounds__(256) void gemm_x_kernel(
    const float* __restrict__ A, const f16* __restrict__ Bp,
    const float* __restrict__ biasp, f16* __restrict__ xw)
{
    const int tid = threadIdx.x;
    const int w = tid >> 6, l = tid & 63;
    const int lr = l & 15, lq = l >> 4;
    const int n0 = blockIdx.x * 128;
    const int m0 = blockIdx.y * 128;

    f32x4 acc[2][8];
#pragma unroll
    for (int mt = 0; mt < 2; mt++)
#pragma unroll
        for (int nt = 0; nt < 8; nt++) acc[mt][nt] = (f32x4){0.f, 0.f, 0.f, 0.f};

    const float* a0 = A + (size_t)(m0 + 32 * w + lr) * 1024 + lq * 8;
    const f16x8* bp = (const f16x8*)Bp + (size_t)(n0 >> 4) * (32 * 64) + l;

#pragma unroll 2
    for (int s = 0; s < 32; s++) {
        f16x8 af[2];
#pragma unroll
        for (int mt = 0; mt < 2; mt++) {
            const float* ap = a0 + mt * (16 * 1024) + 32 * s;
            float4 v0 = *(const float4*)ap;
            float4 v1 = *(const float4*)(ap + 4);
            f16x8 tt;
            tt[0] = (f16)v0.x; tt[1] = (f16)v0.y; tt[2] = (f16)v0.z; tt[3] = (f16)v0.w;
            tt[4] = (f16)v1.x; tt[5] = (f16)v1.y; tt[6] = (f16)v1.z; tt[7] = (f16)v1.w;
            af[mt] = tt;
        }
#pragma unroll
        for (int nt = 0; nt < 8; nt++) {
            f16x8 bfr = bp[(size_t)(nt * 32 + s) * 64];
            acc[0][nt] = __builtin_amdgcn_mfma_f32_16x16x32_f16(af[0], bfr, acc[0][nt], 0, 0, 0);
            acc[1][nt] = __builtin_amdgcn_mfma_f32_16x16x32_f16(af[1], bfr, acc[1][nt], 0, 0, 0);
        }
    }
#pragma unroll
    for (int nt = 0; nt < 8; nt++) {
        int n = n0 + nt * 16 + lr;
        float bias = biasp[n];
#pragma unroll
        for (int mt = 0; mt < 2; mt++) {
#pragma unroll
            for (int r = 0; r < 4; r++) {
                int m = m0 + 32 * w + mt * 16 + lq * 4 + r;
                xw[(size_t)m * NTOT + n] = (f16)(acc[mt][nt][r] + bias);
            }
        }
    }
}

// ---------------------------------------------------------------------------
// Phase 2: persistent recurrent kernel, batch-grouped + DATAFLOW chunk sync.
// 256 WGs x 256 thr. Group g = blockIdx&3 (16 batch rows), member j2 =
// blockIdx>>2 (64 gate cols). Weights: 128 KB dynamic LDS. Wave wv computes
// the 16-row tile x gate cols [16wv,+16) over k=1024 (32 MFMAs), consumed in
// 4 chunks of 8 k-slices; chunk c needs only producers 16c..16c+16, polled
// inline (spin overlaps in-flight loads; later chunks' skew hides under
// MFMA). ONE __syncthreads per step (pre_lds handoff, double-buffered).
// Activation: tid<64 (wave 0), ONE coherent u64 h store -> next virgin ring
// slot, vmcnt(0), flag store = t+1. No trailing barrier: waves 1-3 are
// already polling next step's chunk 0.
// ---------------------------------------------------------------------------
__global__ __launch_bounds__(256, 1) void lstm_persist_ring(
    const f16* __restrict__ xw, const f16* __restrict__ whp,
    const int* __restrict__ lengths, const float* __restrict__ c0,
    float* __restrict__ out, f16* ring, unsigned int* flags)
{
    extern __shared__ __align__(16) char smem[];
    f16*   wlds    = (f16*)smem;                  // 128 KB weight fragments (4 n-tiles)
    float* pre_lds = (float*)(smem + 131072);     // 2 x 16 x 68 f32 (double buffer)

    const int g  = blockIdx.x & 3;
    const int j2 = blockIdx.x >> 2;
    const int tid = threadIdx.x;
    const int wv = tid >> 6, l = tid & 63;
    const int lr = l & 15, lq = l >> 4;

    // stage this WG's 128 KB of recurrent-weight fragments (n-tiles 4*j2..+4)
    {
        const f16x8* wp = (const f16x8*)whp + (size_t)(4 * j2) * 2048;
        f16x8* wl0 = (f16x8*)wlds;
        for (int i = tid; i < 8192; i += 256) wl0[i] = wp[i];
    }
    __syncthreads();

    const int koff = lq * 8;
    const f16x8* wl = (const f16x8*)wlds + wv * 2048 + l;   // wave wv's n-tile; + s*64 per slice

    unsigned int* myflag = flags + (unsigned int)g * 1024u + (unsigned int)j2 * 16u;
    const unsigned int* pollp = flags + (unsigned int)g * 1024u + (unsigned int)(l & 15) * 16u;
    // chunk c: lane l watches member 16c + (l&15)  ->  pollp + c*256

    // activation mapping (tid < 64): thread (b_local, q) owns h cols 16*j2+4q..+4
    const int b_local = tid >> 2, q = tid & 3;
    const int b_glob  = 16 * g + b_local;
    float cA = 0.f, cB = 0.f, cC = 0.f, cD = 0.f;
    int len = 0;
    const f16* xwbase = nullptr;
    f16x8 xg0 = (f16x8)0, xg1 = (f16x8)0;
    if (tid < 64) {
        float4 ci = *(const float4*)&c0[16 * j2 + 4 * q];
        cA = ci.x; cB = ci.y; cC = ci.z; cD = ci.w;
        len = lengths[b_glob];
        xwbase = xw + (size_t)b_glob * NTOT + 64 * j2 + 16 * q;   // 16 gate cols window
        xg0 = *(const f16x8*)xwbase;                              // step-0 x-contribution
        xg1 = *(const f16x8*)(xwbase + 8);
    }

    const size_t slab = (size_t)g * GSLAB_H;

    for (int t = 0; t < T_STEPS; t++) {
        const f16* hb = ring + (size_t)t * RSTRIDE_H + slab;     // virgin slot, this group's rows
        const f16x8* ap = (const f16x8*)(hb + (size_t)lr * DD + koff);  // + s*4 per slice

        // prefetch next step's xw slice (read-only; in flight during chunk-0 spin)
        f16x8 xg0n = xg0, xg1n = xg1;
        if (tid < 64 && t + 1 < T_STEPS) {
            const f16* nx = xwbase + (size_t)(t + 1) * (BATCH * NTOT);
            xg0n = *(const f16x8*)nx;
            xg1n = *(const f16x8*)(nx + 8);
        }

        const unsigned int want = (unsigned int)t;   // flag==t means slot t ready
        f32x4 acc0 = {0.f, 0.f, 0.f, 0.f}, acc1 = {0.f, 0.f, 0.f, 0.f};

        // chunk 0 gate (t=0: slot prewritten by prepack, kernel-order visible)
        if (t > 0) {
            while (!__all(load_coh_u32(pollp + 0 * 256) >= want))
                __builtin_amdgcn_s_sleep(1);
            asm volatile("" ::: "memory");
        }

#pragma unroll
        for (int c = 0; c < 4; c++) {
            // issue chunk c's h loads (producers already observed)
            f16x8 a[8];
            const f16x8* apc = ap + 32 * c;
#pragma unroll
            for (int i = 0; i < 8; i++) a[i] = apc[4 * i];

            // poll chunk c+1 while chunk-c loads are in flight (spin's
            // vmcnt(0) absorbs their latency)
            if (t > 0 && c < 3) {
                while (!__all(load_coh_u32(pollp + (c + 1) * 256) >= want))
                    __builtin_amdgcn_s_sleep(1);
                asm volatile("" ::: "memory");
            }

            const f16x8* wlc = wl + 64 * (8 * c);
#pragma unroll
            for (int i = 0; i < 8; i += 2) {
                acc0 = __builtin_amdgcn_mfma_f32_16x16x32_f16(a[i],     wlc[64 * i],       acc0, 0, 0, 0);
                acc1 = __builtin_amdgcn_mfma_f32_16x16x32_f16(a[i + 1], wlc[64 * (i + 1)], acc1, 0, 0, 0);
            }
        }
        f32x4 pre = acc0 + acc1;

        // D layout: row = lq*4 + r (batch local), col = 16*wv + lr (gate col)
        float* pb = pre_lds + (size_t)(t & 1) * (16 * 68);
#pragma unroll
        for (int r = 0; r < 4; r++)
            pb[(lq * 4 + r) * 68 + 16 * wv + lr] = pre[r];
        __syncthreads();      // ONE barrier per step: pre handoff to wave 0

        if (tid < 64) {
            const float* pr = &pb[b_local * 68 + 16 * q];
            float4 g0 = *(const float4*)(pr + 0);
            float4 g1 = *(const float4*)(pr + 4);
            float4 g2 = *(const float4*)(pr + 8);
            float4 g3 = *(const float4*)(pr + 12);
            float h0, h1, h2, h3;
            GATE4(g0, xg0[0], xg0[1], xg0[2], xg0[3], cA, h0);
            GATE4(g1, xg0[4], xg0[5], xg0[6], xg0[7], cB, h1);
            GATE4(g2, xg1[0], xg1[1], xg1[2], xg1[3], cC, h2);
            GATE4(g3, xg1[4], xg1[5], xg1[6], xg1[7], cD, h3);
            if (t >= len) { h0 = 0.f; h1 = 0.f; h2 = 0.f; h3 = 0.f; }  // ref: mask carried+emitted
            if (t + 1 < T_STEPS) {
                f16x4 hv;
                hv[0] = (f16)h0; hv[1] = (f16)h1; hv[2] = (f16)h2; hv[3] = (f16)h3;
                store_coh_u64((unsigned long long*)(ring + (size_t)(t + 1) * RSTRIDE_H + slab
                                                    + (size_t)b_local * DD + 16 * j2 + 4 * q),
                              __builtin_bit_cast(unsigned long long, hv));
                waitcnt_vm0();                    // h sliver acked at coherency point
                if (tid == 0) store_coh_u32(myflag, (unsigned int)(t + 1));
            }
            // out store off the critical path (after flag)
            *(float4*)(out + (size_t)t * (BATCH * DD) + (size_t)b_glob * DD
                       + 16 * j2 + 4 * q) = (float4){h0, h1, h2, h3};
        }
        // no trailing barrier: waves 1-3 proceed straight into next step's
        // chunk-0 poll; pre_lds is double-buffered so their writes target the
        // other buffer, and their chunk containing this WG's own flag bounds
        // intra-WG skew.
        xg0 = xg0n; xg1 = xg1n;
    }
}

// ---------------------------------------------------------------------------
extern "C" void kernel_launch(void* const* d_in, const int* in_sizes, int n_in,
                              void* d_out, int out_size, void* d_ws, size_t ws_size,
                              hipStream_t stream) {
    const float* batch   = (const float*)d_in[0];
    const int*   lengths = (const int*)d_in[1];
    const float* c0      = (const float*)d_in[2];
    const float* Wi = (const float*)d_in[3];
    const float* bi = (const float*)d_in[4];
    const float* Wf = (const float*)d_in[5];
    const float* bf = (const float*)d_in[6];
    const float* Wc = (const float*)d_in[7];
    const float* bc = (const float*)d_in[8];
    const float* Wo = (const float*)d_in[9];
    const float* bo = (const float*)d_in[10];
    float* out = (float*)d_out;

    char* ws = (char*)d_ws;
    unsigned int* flags = (unsigned int*)(ws + OFF_FLAGS);
    float* biasp = (float*)(ws + OFF_BIAS);
    f16*   whp   = (f16*)(ws + OFF_WHP);
    f16*   bxp   = (f16*)(ws + OFF_BXP);
    f16*   xw    = (f16*)(ws + OFF_XW);
    f16*   ring  = (f16*)(ws + OFF_RING);

    prepack_kernel<<<33040, 256, 0, stream>>>(Wi, Wf, Wc, Wo, bi, bf, bc, bo, c0,
                                              whp, bxp, biasp, ring, flags);
    gemm_x_kernel<<<dim3(32, 256), 256, 0, stream>>>(batch, bxp, biasp, xw);
    // dynamic LDS: 128 KB weights + 2*16*68*4 B pre = 139776 B (<160 KB/CU)
    lstm_persist_ring<<<256, 256, 139776, stream>>>(xw, whp, lengths, c0, out, ring, flags);
}